// Round 3
// baseline (1526.132 us; speedup 1.0000x reference)
//
#include <hip/hip_runtime.h>
#include <cstdint>

#define BB 128
#define DD 512
#define SS 30
#define PP 196
#define TT 12
#define BD (BB*DD)

// ---------------------------------------------------------------------------
// gemm4: out[m0..m0+8, nchunk] = epi( sum over nparts*512 K of A_p @ W_p ).
// All K-parts are 512 wide. block = 256 (4 waves, wave = K-split), LDS reduce.
// A rows: scalar (uniform) loads; W: lane-coalesced. grid (M/8, N/64, z).
// epi: 0 +bias | 1 sigmoid(+bias) | 2 gate(g=e1, mprev=e2, +bias)
//      3 N=1024 split: n<512 -> out=acc*e1 ; n>=512 -> o2=acc  (no bias)
//      4 out = acc + e1[m,n] (row addend) | 6 raw
// ---------------------------------------------------------------------------
struct GDesc {
    const float* A0; const float* A1; const float* A2;
    const float* W0; const float* W1; const float* W2;
    const float* bias;
    float* out;
    const float* e1; const float* e2; float* o2;
    int nparts, epi, nblk, N;
};

__global__ __launch_bounds__(256)
void gemm4(GDesc da, GDesc db)
{
    GDesc d = (blockIdx.z == 0) ? da : db;
    if ((int)blockIdx.y >= d.nblk) return;
    const int lane = threadIdx.x & 63;
    const int w    = threadIdx.x >> 6;
    const int m0   = blockIdx.x * 8;
    const int n    = blockIdx.y * 64 + lane;
    const size_t N = (size_t)d.N;

    float acc[8];
    #pragma unroll
    for (int m = 0; m < 8; ++m) acc[m] = 0.f;

    const int Kq = d.nparts * 128;
    const int k0 = w * Kq, k1 = k0 + Kq;
    for (int p = 0; p < d.nparts; ++p) {
        const int pb = p * 512;
        int lo = k0 > pb ? k0 : pb;
        int hi = (k1 < pb + 512) ? k1 : pb + 512;
        if (lo >= hi) continue;
        const float* A  = (p == 0) ? d.A0 : (p == 1 ? d.A1 : d.A2);
        const float* Wb = (p == 0) ? d.W0 : (p == 1 ? d.W1 : d.W2);
        const float* a  = A + (size_t)m0 * 512;
        for (int k = lo; k < hi; k += 4) {
            const int kk = k - pb;
            const float* wp = Wb + (size_t)kk * N + n;
            float w0 = wp[0];
            float w1 = wp[N];
            float w2 = wp[2*N];
            float w3 = wp[3*N];
            #pragma unroll
            for (int m = 0; m < 8; ++m) {
                const float* am = a + m*512 + kk;
                float v = fmaf(am[0], w0, acc[m]);
                v       = fmaf(am[1], w1, v);
                v       = fmaf(am[2], w2, v);
                acc[m]  = fmaf(am[3], w3, v);
            }
        }
    }

    __shared__ float red[4][8][64];
    #pragma unroll
    for (int m = 0; m < 8; ++m) red[w][m][lane] = acc[m];
    __syncthreads();

    for (int i = threadIdx.x; i < 512; i += 256) {
        int mm = i >> 6, nl = i & 63;
        int nn = blockIdx.y * 64 + nl;
        float s = ((red[0][mm][nl] + red[1][mm][nl]) +
                   (red[2][mm][nl] + red[3][mm][nl]));
        size_t row = (size_t)(m0 + mm);
        if (d.epi == 0) {
            d.out[row*512 + nn] = s + d.bias[nn];
        } else if (d.epi == 1) {
            float v = s + d.bias[nn];
            d.out[row*512 + nn] = 1.f / (1.f + __expf(-v));
        } else if (d.epi == 2) {
            float v = s + d.bias[nn];
            float g = d.e1[row*512 + nn];
            d.out[row*512 + nn] = g * d.e2[row*512 + nn] + (1.f - g) * v;
        } else if (d.epi == 3) {
            if (nn < 512) d.out[row*512 + nn] = s * d.e1[row*512 + nn];
            else          d.o2[row*512 + (nn - 512)] = s;
        } else if (d.epi == 4) {
            d.out[row*512 + nn] = s + d.e1[row*512 + nn];
        } else {
            d.out[row*512 + nn] = s;
        }
    }
}

// ---------------------------------------------------------------------------
// vecmat: out[n] = sum_k v[k]*W[k*512+n] + bias[n].  grid 8, block 256.
// ---------------------------------------------------------------------------
__global__ __launch_bounds__(256)
void vecmat(const float* __restrict__ v, const float* __restrict__ W,
            const float* __restrict__ bias, float* __restrict__ out)
{
    int lane = threadIdx.x & 63, w = threadIdx.x >> 6;
    int n = blockIdx.x * 64 + lane;
    float s = 0.f;
    for (int k = w*128; k < w*128 + 128; ++k)
        s = fmaf(v[k], W[(size_t)k*512 + n], s);
    __shared__ float red[4][64];
    red[w][lane] = s;
    __syncthreads();
    if (threadIdx.x < 64) {
        int nn = blockIdx.x * 64 + threadIdx.x;
        out[nn] = red[0][threadIdx.x] + red[1][threadIdx.x]
                + red[2][threadIdx.x] + red[3][threadIdx.x] + bias[nn];
    }
}

// ---------------------------------------------------------------------------
// Tiled transpose: dst[c*R + r] = src[r*C + c].  grid (C/32, R/32), block 256.
// ---------------------------------------------------------------------------
__global__ __launch_bounds__(256)
void transpose_k(const float* __restrict__ src, float* __restrict__ dst,
                 int R, int C)
{
    __shared__ float tile[32][33];
    int bx = blockIdx.x * 32, by = blockIdx.y * 32;
    int tx = threadIdx.x & 31, ty = threadIdx.x >> 5;
    #pragma unroll
    for (int i = 0; i < 32; i += 8)
        tile[ty + i][tx] = src[(size_t)(by + ty + i) * C + bx + tx];
    __syncthreads();
    #pragma unroll
    for (int i = 0; i < 32; i += 8)
        dst[(size_t)(bx + ty + i) * R + by + tx] = tile[tx][ty + i];
}

// cwsT[b][s][d] = cws[b][d][s].  grid (128, 16), block 256.
__global__ __launch_bounds__(256)
void transpose_cws(const float* __restrict__ cws, float* __restrict__ cwsT)
{
    int b = blockIdx.x, dc = blockIdx.y;
    __shared__ float tile[32][33];
    int tid = threadIdx.x;
    const float* src = cws + ((size_t)b*DD + dc*32) * SS;
    for (int i = tid; i < 1024; i += 256) {
        int r = i >> 5, s = i & 31;
        if (s < SS) tile[r][s] = src[(size_t)r*SS + s];
    }
    __syncthreads();
    for (int i = tid; i < 1024; i += 256) {
        int s = i >> 5, r = i & 31;
        if (s < SS)
            cwsT[((size_t)b*SS + s)*DD + dc*32 + r] = tile[r][s];
    }
}

// ---------------------------------------------------------------------------
// step_control: per-b block (512 thr). clog (coalesced via cwsT) -> softmax ->
// c_i; writes c_hist[t+1], v=c_i*wra, self-attn m_sa.
// ---------------------------------------------------------------------------
__global__ __launch_bounds__(512)
void step_control(const float* __restrict__ cq, const float* __restrict__ cws,
                  const float* __restrict__ cwsT,
                  const float* __restrict__ wca, const float* __restrict__ bca,
                  const float* __restrict__ wra, const float* __restrict__ wwa,
                  const float* __restrict__ bwa,
                  float* __restrict__ c_hist, const float* __restrict__ m_hist,
                  float* __restrict__ vbuf, float* __restrict__ m_sa, int t)
{
    int b = blockIdx.x;
    int tid = threadIdx.x;
    int lane = tid & 63, w = tid >> 6;
    __shared__ float cqw[DD];
    __shared__ float ciw[DD];
    __shared__ float clog[32];
    __shared__ float cattn[32];
    __shared__ float slog[16];
    __shared__ float sattn[16];

    cqw[tid] = cq[(size_t)b*DD + tid] * wca[tid];
    __syncthreads();

    // clog[s] = cqw . cwsT[b,s,:]  (coalesced)
    for (int s = w; s < SS; s += 8) {
        const float* row = cwsT + ((size_t)b*SS + s)*DD;
        float a = 0.f;
        #pragma unroll
        for (int j = 0; j < 8; ++j)
            a = fmaf(cqw[lane + 64*j], row[lane + 64*j], a);
        for (int off = 32; off; off >>= 1) a += __shfl_xor(a, off, 64);
        if (lane == 0) clog[s] = a;
    }
    __syncthreads();

    if (tid < 32) {
        float v = (tid < SS) ? clog[tid] + bca[0] : -1e30f;
        float mx = v;
        for (int off = 16; off; off >>= 1) mx = fmaxf(mx, __shfl_xor(mx, off, 32));
        float e = (tid < SS) ? __expf(v - mx) : 0.f;
        float sm = e;
        for (int off = 16; off; off >>= 1) sm += __shfl_xor(sm, off, 32);
        cattn[tid] = e / sm;
    }
    __syncthreads();

    {   // c_i: thread-per-d, contiguous 30-float read
        int d = tid;
        const float* base = cws + (size_t)b*DD*SS + (size_t)d*SS;
        float acc = 0.f;
        #pragma unroll
        for (int j = 0; j < SS; ++j) acc = fmaf(cattn[j], base[j], acc);
        c_hist[(size_t)(t+1)*BD + (size_t)b*DD + d] = acc;
        vbuf[(size_t)b*DD + d] = acc * wra[d];
        ciw[d] = acc * wwa[d];
    }
    __syncthreads();

    for (int tp = w; tp <= t; tp += 8) {
        const float* ch = c_hist + (size_t)tp*BD + (size_t)b*DD;
        float a = 0.f;
        #pragma unroll
        for (int j = 0; j < 8; ++j)
            a = fmaf(ciw[lane + 64*j], ch[lane + 64*j], a);
        for (int off = 32; off; off >>= 1) a += __shfl_xor(a, off, 64);
        if (lane == 0) slog[tp] = a;
    }
    __syncthreads();

    if (tid < 16) {
        float v = (tid <= t) ? (slog[tid] + bwa[0]) : -1e30f;
        float mx = v;
        for (int off = 8; off; off >>= 1) mx = fmaxf(mx, __shfl_xor(mx, off, 16));
        float e = (tid <= t) ? __expf(v - mx) : 0.f;
        float sm = e;
        for (int off = 8; off; off >>= 1) sm += __shfl_xor(sm, off, 16);
        sattn[tid] = e / sm;
    }
    __syncthreads();

    {   // m_sa: thread-per-d
        int d = tid;
        float acc = 0.f;
        for (int tp = 0; tp <= t; ++tp)
            acc = fmaf(sattn[tp], m_hist[(size_t)tp*BD + (size_t)b*DD + d], acc);
        m_sa[(size_t)b*DD + d] = acc;
    }
}

// ---------------------------------------------------------------------------
// read1: block (b, dg). Partial rlog over 64-d slice: rlog_p = KB.y
// ---------------------------------------------------------------------------
__global__ __launch_bounds__(256)
void read1(const float* __restrict__ KB, const float* __restrict__ y,
           float* __restrict__ rlogp)
{
    int b = blockIdx.x, dg = blockIdx.y, tid = threadIdx.x;
    __shared__ float yb[64];
    if (tid < 64) yb[tid] = y[(size_t)b*DD + dg*64 + tid];
    __syncthreads();
    float a0=0.f, a1=0.f, a2=0.f, a3=0.f;
    if (tid < PP) {
        const float* kb = KB + ((size_t)b*DD + dg*64)*PP + tid;
        #pragma unroll 4
        for (int dd = 0; dd < 64; dd += 4) {
            a0 = fmaf(kb[(size_t)(dd+0)*PP], yb[dd+0], a0);
            a1 = fmaf(kb[(size_t)(dd+1)*PP], yb[dd+1], a1);
            a2 = fmaf(kb[(size_t)(dd+2)*PP], yb[dd+2], a2);
            a3 = fmaf(kb[(size_t)(dd+3)*PP], yb[dd+3], a3);
        }
    }
    rlogp[((size_t)b*8 + dg)*256 + tid] = (a0+a1)+(a2+a3);
}

// ---------------------------------------------------------------------------
// read2: reduce partials -> softmax(196) -> m_new 64-d slice.
// ---------------------------------------------------------------------------
__global__ __launch_bounds__(256)
void read2(const float* __restrict__ KB, const float* __restrict__ rlogp,
           float* __restrict__ m_new)
{
    int b = blockIdx.x, dg = blockIdx.y;
    int tid = threadIdx.x, lane = tid & 63, w = tid >> 6;
    __shared__ float ex[256];
    __shared__ float wred[4];

    float v = -1e30f;
    if (tid < PP) {
        const float* rp = rlogp + (size_t)b*2048 + tid;
        float t0 = rp[0]    + rp[256];
        float t1 = rp[512]  + rp[768];
        float t2 = rp[1024] + rp[1280];
        float t3 = rp[1536] + rp[1792];
        v = (t0+t1)+(t2+t3);
    }
    float mx = v;
    for (int off = 32; off; off >>= 1) mx = fmaxf(mx, __shfl_xor(mx, off, 64));
    if (lane == 0) wred[w] = mx;
    __syncthreads();
    float gmax = fmaxf(fmaxf(wred[0], wred[1]), fmaxf(wred[2], wred[3]));
    float e = (tid < PP) ? __expf(v - gmax) : 0.f;
    float sm = e;
    for (int off = 32; off; off >>= 1) sm += __shfl_xor(sm, off, 64);
    __syncthreads();
    if (lane == 0) wred[w] = sm;
    __syncthreads();
    float inv = 1.f / ((wred[0]+wred[1]) + (wred[2]+wred[3]));
    ex[tid] = e * inv;
    __syncthreads();

    #pragma unroll 4
    for (int i = 0; i < 16; ++i) {
        int d = dg*64 + w*16 + i;
        const float* row = KB + ((size_t)b*DD + d)*PP;
        float a = ex[lane]       * row[lane]
                + ex[lane + 64]  * row[lane + 64]
                + ex[lane + 128] * row[lane + 128];
        if (lane < PP - 192) a = fmaf(ex[lane + 192], row[lane + 192], a);
        for (int off = 32; off; off >>= 1) a += __shfl_xor(a, off, 64);
        if (lane == 0) m_new[(size_t)b*DD + d] = a;
    }
}

__global__ __launch_bounds__(256)
void init_hist(const float* __restrict__ c0, const float* __restrict__ m0,
               float* __restrict__ c_hist, float* __restrict__ m_hist)
{
    int i = blockIdx.x * 256 + threadIdx.x;
    if (i < BD) { c_hist[i] = c0[i]; m_hist[i] = m0[i]; }
}

// ---------------------------------------------------------------------------
extern "C" void kernel_launch(void* const* d_in, const int* in_sizes, int n_in,
                              void* d_out, int out_size, void* d_ws, size_t ws_size,
                              hipStream_t stream)
{
    (void)in_sizes; (void)n_in; (void)out_size; (void)ws_size;
    const float* q   = (const float*)d_in[0];
    const float* cws = (const float*)d_in[1];
    const float* KB  = (const float*)d_in[2];
    const float* c0  = (const float*)d_in[3];
    const float* m0  = (const float*)d_in[4];
    const float* Wq  = (const float*)d_in[5];
    const float* bq  = (const float*)d_in[6];
    const float* Wct = (const float*)d_in[7];
    const float* bct = (const float*)d_in[8];
    const float* wca = (const float*)d_in[9];
    const float* bca = (const float*)d_in[10];
    const float* Wm  = (const float*)d_in[11];
    const float* bm  = (const float*)d_in[12];
    const float* Wkb = (const float*)d_in[13];
    // d_in[14] = bkb : softmax-shift-invariant, dropped
    const float* Wrm = (const float*)d_in[15];
    // d_in[16] = brm, d_in[18] = bra : dropped (softmax-shift-invariant)
    const float* wra = (const float*)d_in[17];
    const float* Wwm = (const float*)d_in[19];
    const float* bwm = (const float*)d_in[20];
    const float* wwa = (const float*)d_in[21];
    const float* bwa = (const float*)d_in[22];
    const float* Wam = (const float*)d_in[23];
    const float* bam = (const float*)d_in[24];
    const float* Wg  = (const float*)d_in[25];
    const float* bg  = (const float*)d_in[26];
    // d_in[27] = steps == 12 (hardcoded TT)

    float* ws     = (float*)d_ws;
    float* q_i    = ws;
    float* c_hist = ws + 1*BD;       // 13*BD
    float* m_hist = ws + 14*BD;      // 13*BD
    float* cqb    = ws + 27*BD;
    float* mp     = ws + 28*BD;
    float* vbuf   = ws + 29*BD;
    float* w1     = ws + 30*BD;
    float* vW     = ws + 31*BD;
    float* gbuf   = ws + 32*BD;
    float* m_sa   = ws + 33*BD;
    float* m_new  = ws + 34*BD;
    float* ybuf   = ws + 35*BD;
    float* rlogp  = ws + 36*BD;      // 4*BD
    float* WrmT   = ws + 40*BD;      // 8*BD (512x1024)
    float* WkbT   = ws + 48*BD;      // 4*BD
    float* WA     = ws + 52*BD;      // 4*BD
    float* WB     = ws + 56*BD;      // 4*BD
    float* qct    = ws + 60*BD;      // 1*BD
    float* b2     = ws + 61*BD;      // 512
    float* cwsT   = ws + 62*BD;      // 30*BD (128*30*512)

    const float* Wct_bot = Wct + 262144;   // rows 512..1023
    const float* Wam_bot = Wam + 262144;
    const float* Wwm_bot = Wwm + 262144;
    dim3 blk(256);
    GDesc Z = { nullptr,nullptr,nullptr, nullptr,nullptr,nullptr,
                nullptr, nullptr, nullptr,nullptr,nullptr, 1,6,0,512 };

    // ---- setup ----
    init_hist<<<dim3(BD/256), blk, 0, stream>>>(c0, m0, c_hist, m_hist);
    transpose_k<<<dim3(16,32), blk, 0, stream>>>(Wrm, WrmT, 1024, 512);
    transpose_k<<<dim3(16,16), blk, 0, stream>>>(Wkb, WkbT, 512, 512);
    transpose_cws<<<dim3(128,16), blk, 0, stream>>>(cws, cwsT);

    {   // q_i = q@Wq + bq
        GDesc d = { q,nullptr,nullptr, Wq,nullptr,nullptr, bq, q_i,
                    nullptr,nullptr,nullptr, 1,0,8,512 };
        gemm4<<<dim3(16,8,1), blk, 0, stream>>>(d, Z);
    }
    {   // qct = q_i@Wct_top + bct
        GDesc d = { q_i,nullptr,nullptr, Wct,nullptr,nullptr, bct, qct,
                    nullptr,nullptr,nullptr, 1,0,8,512 };
        gemm4<<<dim3(16,8,1), blk, 0, stream>>>(d, Z);
    }
    {   // WA = Wwm_top@Wam_bot ; WB = Wwm_bot@Wam_bot  (M=512)
        GDesc da = { Wwm,nullptr,nullptr, Wam_bot,nullptr,nullptr, nullptr,
                     WA, nullptr,nullptr,nullptr, 1,6,8,512 };
        GDesc db = { Wwm_bot,nullptr,nullptr, Wam_bot,nullptr,nullptr, nullptr,
                     WB, nullptr,nullptr,nullptr, 1,6,8,512 };
        gemm4<<<dim3(64,8,2), blk, 0, stream>>>(da, db);
    }
    vecmat<<<dim3(8), blk, 0, stream>>>(bwm, Wam_bot, bam, b2);

    // ---- recurrence ----
    for (int t = 0; t < TT; ++t) {
        float* c_prev = c_hist + (size_t)t * BD;
        float* m_prev = m_hist + (size_t)t * BD;
        float* c_i    = c_hist + (size_t)(t+1) * BD;

        {   // cq = c_prev@Wct_bot + qct  ||  mp = m_prev@Wm + bm
            GDesc da = { c_prev,nullptr,nullptr, Wct_bot,nullptr,nullptr,
                         nullptr, cqb, qct,nullptr,nullptr, 1,4,8,512 };
            GDesc db = { m_prev,nullptr,nullptr, Wm,nullptr,nullptr,
                         bm, mp, nullptr,nullptr,nullptr, 1,0,8,512 };
            gemm4<<<dim3(16,8,2), blk, 0, stream>>>(da, db);
        }

        step_control<<<dim3(BB), dim3(512), 0, stream>>>(
            cqb, cws, cwsT, wca, bca, wra, wwa, bwa,
            c_hist, m_hist, vbuf, m_sa, t);

        {   // [w1|vW] = v@WrmT (w1 = u*mp)  ||  g = sigmoid(c_i@Wg+bg)
            GDesc da = { vbuf,nullptr,nullptr, WrmT,nullptr,nullptr,
                         nullptr, w1, mp,nullptr,vW, 1,3,16,1024 };
            GDesc db = { c_i,nullptr,nullptr, Wg,nullptr,nullptr,
                         bg, gbuf, nullptr,nullptr,nullptr, 1,1,8,512 };
            gemm4<<<dim3(16,16,2), blk, 0, stream>>>(da, db);
        }

        {   // y = w1@WkbT + vW
            GDesc d = { w1,nullptr,nullptr, WkbT,nullptr,nullptr,
                        nullptr, ybuf, vW,nullptr,nullptr, 1,4,8,512 };
            gemm4<<<dim3(16,8,1), blk, 0, stream>>>(d, Z);
        }

        read1<<<dim3(BB,8), blk, 0, stream>>>(KB, ybuf, rlogp);
        read2<<<dim3(BB,8), blk, 0, stream>>>(KB, rlogp, m_new);

        {   // m_out = gate( m_sa@Wam_top + m_new@WA + m_prev@WB + b2 )
            float* mout = (t == TT-1) ? (float*)d_out
                                      : (m_hist + (size_t)(t+1) * BD);
            GDesc d = { m_sa, m_new, m_prev, Wam, WA, WB,
                        b2, mout, gbuf, m_prev, nullptr, 3,2,8,512 };
            gemm4<<<dim3(16,8,1), blk, 0, stream>>>(d, Z);
        }
    }
}

// Round 4
// 1252.721 us; speedup vs baseline: 1.2183x; 1.2183x over previous
//
#include <hip/hip_runtime.h>
#include <cstdint>

#define BB 128
#define DD 512
#define SS 30
#define PP 196
#define TT 12
#define BD (BB*DD)

// ---------------------------------------------------------------------------
// gemm4: out[m0..m0+4, nchunk] = epi( sum over nparts*512 K of A_p @ W_p ).
// block = 256 (4 waves; wave w owns k in [w*128,w*128+128) of each part).
// Per thread: 4 m-rows x 2 k-streams = 8 independent FMA chains (ILP),
// LDS reduce across waves. grid (M/4, N/64, z) -- z selects descriptor.
// epi: 0 +bias | 1 sigmoid(+bias) | 2 gate(g=e1, mprev=e2, +bias)
//      3 N=1024 split: n<512 -> out=acc*e1 ; n>=512 -> o2=acc  (no bias)
//      4 out = acc + e1[m,n] (row addend) | 6 raw
// ---------------------------------------------------------------------------
struct GDesc {
    const float* A0; const float* A1; const float* A2;
    const float* W0; const float* W1; const float* W2;
    const float* bias;
    float* out;
    const float* e1; const float* e2; float* o2;
    int nparts, epi, nblk, N;
};

__global__ __launch_bounds__(256)
void gemm4(GDesc da, GDesc db)
{
    GDesc d = (blockIdx.z == 0) ? da : db;
    if ((int)blockIdx.y >= d.nblk) return;
    const int lane = threadIdx.x & 63;
    const int w    = threadIdx.x >> 6;
    const int m0   = blockIdx.x * 4;
    const int n    = blockIdx.y * 64 + lane;
    const size_t N = (size_t)d.N;

    float acc[4][2];
    #pragma unroll
    for (int m = 0; m < 4; ++m) { acc[m][0] = 0.f; acc[m][1] = 0.f; }

    for (int p = 0; p < d.nparts; ++p) {
        const float* A  = (p == 0) ? d.A0 : (p == 1 ? d.A1 : d.A2);
        const float* Wp = (p == 0) ? d.W0 : (p == 1 ? d.W1 : d.W2);
        const float* Wb = Wp + (size_t)(w * 128) * N + n;
        const float* a  = A + (size_t)m0 * 512 + w * 128;
        #pragma unroll 2
        for (int k = 0; k < 128; k += 8) {
            float w0 = Wb[(size_t)(k+0)*N];
            float w1 = Wb[(size_t)(k+1)*N];
            float w2 = Wb[(size_t)(k+2)*N];
            float w3 = Wb[(size_t)(k+3)*N];
            float w4 = Wb[(size_t)(k+4)*N];
            float w5 = Wb[(size_t)(k+5)*N];
            float w6 = Wb[(size_t)(k+6)*N];
            float w7 = Wb[(size_t)(k+7)*N];
            #pragma unroll
            for (int m = 0; m < 4; ++m) {
                const float* am = a + m*512 + k;
                float s0 = acc[m][0], s1 = acc[m][1];
                s0 = fmaf(am[0], w0, s0);  s1 = fmaf(am[4], w4, s1);
                s0 = fmaf(am[1], w1, s0);  s1 = fmaf(am[5], w5, s1);
                s0 = fmaf(am[2], w2, s0);  s1 = fmaf(am[6], w6, s1);
                s0 = fmaf(am[3], w3, s0);  s1 = fmaf(am[7], w7, s1);
                acc[m][0] = s0; acc[m][1] = s1;
            }
        }
    }

    __shared__ float red[4][4][64];
    #pragma unroll
    for (int m = 0; m < 4; ++m) red[w][m][lane] = acc[m][0] + acc[m][1];
    __syncthreads();

    {
        int mm = threadIdx.x >> 6, nl = threadIdx.x & 63;
        int nn = blockIdx.y * 64 + nl;
        float s = ((red[0][mm][nl] + red[1][mm][nl]) +
                   (red[2][mm][nl] + red[3][mm][nl]));
        size_t row = (size_t)(m0 + mm);
        if (d.epi == 0) {
            d.out[row*512 + nn] = s + d.bias[nn];
        } else if (d.epi == 1) {
            float v = s + d.bias[nn];
            d.out[row*512 + nn] = 1.f / (1.f + __expf(-v));
        } else if (d.epi == 2) {
            float v = s + d.bias[nn];
            float g = d.e1[row*512 + nn];
            d.out[row*512 + nn] = g * d.e2[row*512 + nn] + (1.f - g) * v;
        } else if (d.epi == 3) {
            if (nn < 512) d.out[row*512 + nn] = s * d.e1[row*512 + nn];
            else          d.o2[row*512 + (nn - 512)] = s;
        } else if (d.epi == 4) {
            d.out[row*512 + nn] = s + d.e1[row*512 + nn];
        } else {
            d.out[row*512 + nn] = s;
        }
    }
}

// ---------------------------------------------------------------------------
// vecmat: out[n] = sum_k v[k]*W[k*512+n] + bias[n].  grid 8, block 256.
// ---------------------------------------------------------------------------
__global__ __launch_bounds__(256)
void vecmat(const float* __restrict__ v, const float* __restrict__ W,
            const float* __restrict__ bias, float* __restrict__ out)
{
    int lane = threadIdx.x & 63, w = threadIdx.x >> 6;
    int n = blockIdx.x * 64 + lane;
    float s = 0.f;
    for (int k = w*128; k < w*128 + 128; ++k)
        s = fmaf(v[k], W[(size_t)k*512 + n], s);
    __shared__ float red[4][64];
    red[w][lane] = s;
    __syncthreads();
    if (threadIdx.x < 64) {
        int nn = blockIdx.x * 64 + threadIdx.x;
        out[nn] = red[0][threadIdx.x] + red[1][threadIdx.x]
                + red[2][threadIdx.x] + red[3][threadIdx.x] + bias[nn];
    }
}

// ---------------------------------------------------------------------------
// Tiled transpose: dst[c*R + r] = src[r*C + c].  grid (C/32, R/32), block 256.
// ---------------------------------------------------------------------------
__global__ __launch_bounds__(256)
void transpose_k(const float* __restrict__ src, float* __restrict__ dst,
                 int R, int C)
{
    __shared__ float tile[32][33];
    int bx = blockIdx.x * 32, by = blockIdx.y * 32;
    int tx = threadIdx.x & 31, ty = threadIdx.x >> 5;
    #pragma unroll
    for (int i = 0; i < 32; i += 8)
        tile[ty + i][tx] = src[(size_t)(by + ty + i) * C + bx + tx];
    __syncthreads();
    #pragma unroll
    for (int i = 0; i < 32; i += 8)
        dst[(size_t)(bx + ty + i) * R + by + tx] = tile[tx][ty + i];
}

// cwsT[b][s][d] = cws[b][d][s].  grid (128, 16), block 256.
__global__ __launch_bounds__(256)
void transpose_cws(const float* __restrict__ cws, float* __restrict__ cwsT)
{
    int b = blockIdx.x, dc = blockIdx.y;
    __shared__ float tile[32][33];
    int tid = threadIdx.x;
    const float* src = cws + ((size_t)b*DD + dc*32) * SS;
    for (int i = tid; i < 1024; i += 256) {
        int r = i >> 5, s = i & 31;
        if (s < SS) tile[r][s] = src[(size_t)r*SS + s];
    }
    __syncthreads();
    for (int i = tid; i < 1024; i += 256) {
        int s = i >> 5, r = i & 31;
        if (s < SS)
            cwsT[((size_t)b*SS + s)*DD + dc*32 + r] = tile[r][s];
    }
}

// ---------------------------------------------------------------------------
// step_control: per-b block (512 thr). clog (coalesced via cwsT) -> softmax ->
// c_i; writes c_hist[t+1], v=c_i*wra, self-attn m_sa.
// ---------------------------------------------------------------------------
__global__ __launch_bounds__(512)
void step_control(const float* __restrict__ cq, const float* __restrict__ cws,
                  const float* __restrict__ cwsT,
                  const float* __restrict__ wca, const float* __restrict__ bca,
                  const float* __restrict__ wra, const float* __restrict__ wwa,
                  const float* __restrict__ bwa,
                  float* __restrict__ c_hist, const float* __restrict__ m_hist,
                  float* __restrict__ vbuf, float* __restrict__ m_sa, int t)
{
    int b = blockIdx.x;
    int tid = threadIdx.x;
    int lane = tid & 63, w = tid >> 6;
    __shared__ float cqw[DD];
    __shared__ float ciw[DD];
    __shared__ float clog[32];
    __shared__ float cattn[32];
    __shared__ float slog[16];
    __shared__ float sattn[16];

    cqw[tid] = cq[(size_t)b*DD + tid] * wca[tid];
    __syncthreads();

    for (int s = w; s < SS; s += 8) {
        const float* row = cwsT + ((size_t)b*SS + s)*DD;
        float a = 0.f;
        #pragma unroll
        for (int j = 0; j < 8; ++j)
            a = fmaf(cqw[lane + 64*j], row[lane + 64*j], a);
        for (int off = 32; off; off >>= 1) a += __shfl_xor(a, off, 64);
        if (lane == 0) clog[s] = a;
    }
    __syncthreads();

    if (tid < 32) {
        float v = (tid < SS) ? clog[tid] + bca[0] : -1e30f;
        float mx = v;
        for (int off = 16; off; off >>= 1) mx = fmaxf(mx, __shfl_xor(mx, off, 32));
        float e = (tid < SS) ? __expf(v - mx) : 0.f;
        float sm = e;
        for (int off = 16; off; off >>= 1) sm += __shfl_xor(sm, off, 32);
        cattn[tid] = e / sm;
    }
    __syncthreads();

    {   // c_i: thread-per-d, contiguous 30-float read
        int d = tid;
        const float* base = cws + (size_t)b*DD*SS + (size_t)d*SS;
        float acc = 0.f;
        #pragma unroll
        for (int j = 0; j < SS; ++j) acc = fmaf(cattn[j], base[j], acc);
        c_hist[(size_t)(t+1)*BD + (size_t)b*DD + d] = acc;
        vbuf[(size_t)b*DD + d] = acc * wra[d];
        ciw[d] = acc * wwa[d];
    }
    __syncthreads();

    for (int tp = w; tp <= t; tp += 8) {
        const float* ch = c_hist + (size_t)tp*BD + (size_t)b*DD;
        float a = 0.f;
        #pragma unroll
        for (int j = 0; j < 8; ++j)
            a = fmaf(ciw[lane + 64*j], ch[lane + 64*j], a);
        for (int off = 32; off; off >>= 1) a += __shfl_xor(a, off, 64);
        if (lane == 0) slog[tp] = a;
    }
    __syncthreads();

    if (tid < 16) {
        float v = (tid <= t) ? (slog[tid] + bwa[0]) : -1e30f;
        float mx = v;
        for (int off = 8; off; off >>= 1) mx = fmaxf(mx, __shfl_xor(mx, off, 16));
        float e = (tid <= t) ? __expf(v - mx) : 0.f;
        float sm = e;
        for (int off = 8; off; off >>= 1) sm += __shfl_xor(sm, off, 16);
        sattn[tid] = e / sm;
    }
    __syncthreads();

    {   // m_sa: thread-per-d
        int d = tid;
        float acc = 0.f;
        for (int tp = 0; tp <= t; ++tp)
            acc = fmaf(sattn[tp], m_hist[(size_t)tp*BD + (size_t)b*DD + d], acc);
        m_sa[(size_t)b*DD + d] = acc;
    }
}

// ---------------------------------------------------------------------------
// read1: block (b, dg). Partial rlog over 64-d slice: rlog_p = KB.y
// ---------------------------------------------------------------------------
__global__ __launch_bounds__(256)
void read1(const float* __restrict__ KB, const float* __restrict__ y,
           float* __restrict__ rlogp)
{
    int b = blockIdx.x, dg = blockIdx.y, tid = threadIdx.x;
    __shared__ float yb[64];
    if (tid < 64) yb[tid] = y[(size_t)b*DD + dg*64 + tid];
    __syncthreads();
    float a0=0.f, a1=0.f, a2=0.f, a3=0.f;
    if (tid < PP) {
        const float* kb = KB + ((size_t)b*DD + dg*64)*PP + tid;
        #pragma unroll 4
        for (int dd = 0; dd < 64; dd += 4) {
            a0 = fmaf(kb[(size_t)(dd+0)*PP], yb[dd+0], a0);
            a1 = fmaf(kb[(size_t)(dd+1)*PP], yb[dd+1], a1);
            a2 = fmaf(kb[(size_t)(dd+2)*PP], yb[dd+2], a2);
            a3 = fmaf(kb[(size_t)(dd+3)*PP], yb[dd+3], a3);
        }
    }
    rlogp[((size_t)b*8 + dg)*256 + tid] = (a0+a1)+(a2+a3);
}

// ---------------------------------------------------------------------------
// read2: reduce partials -> softmax(196) -> m_new 64-d slice.
// ---------------------------------------------------------------------------
__global__ __launch_bounds__(256)
void read2(const float* __restrict__ KB, const float* __restrict__ rlogp,
           float* __restrict__ m_new)
{
    int b = blockIdx.x, dg = blockIdx.y;
    int tid = threadIdx.x, lane = tid & 63, w = tid >> 6;
    __shared__ float ex[256];
    __shared__ float wred[4];

    float v = -1e30f;
    if (tid < PP) {
        const float* rp = rlogp + (size_t)b*2048 + tid;
        float t0 = rp[0]    + rp[256];
        float t1 = rp[512]  + rp[768];
        float t2 = rp[1024] + rp[1280];
        float t3 = rp[1536] + rp[1792];
        v = (t0+t1)+(t2+t3);
    }
    float mx = v;
    for (int off = 32; off; off >>= 1) mx = fmaxf(mx, __shfl_xor(mx, off, 64));
    if (lane == 0) wred[w] = mx;
    __syncthreads();
    float gmax = fmaxf(fmaxf(wred[0], wred[1]), fmaxf(wred[2], wred[3]));
    float e = (tid < PP) ? __expf(v - gmax) : 0.f;
    float sm = e;
    for (int off = 32; off; off >>= 1) sm += __shfl_xor(sm, off, 64);
    __syncthreads();
    if (lane == 0) wred[w] = sm;
    __syncthreads();
    float inv = 1.f / ((wred[0]+wred[1]) + (wred[2]+wred[3]));
    ex[tid] = e * inv;
    __syncthreads();

    #pragma unroll 4
    for (int i = 0; i < 16; ++i) {
        int d = dg*64 + w*16 + i;
        const float* row = KB + ((size_t)b*DD + d)*PP;
        float a = ex[lane]       * row[lane]
                + ex[lane + 64]  * row[lane + 64]
                + ex[lane + 128] * row[lane + 128];
        if (lane < PP - 192) a = fmaf(ex[lane + 192], row[lane + 192], a);
        for (int off = 32; off; off >>= 1) a += __shfl_xor(a, off, 64);
        if (lane == 0) m_new[(size_t)b*DD + d] = a;
    }
}

__global__ __launch_bounds__(256)
void init_hist(const float* __restrict__ c0, const float* __restrict__ m0,
               float* __restrict__ c_hist, float* __restrict__ m_hist)
{
    int i = blockIdx.x * 256 + threadIdx.x;
    if (i < BD) { c_hist[i] = c0[i]; m_hist[i] = m0[i]; }
}

// ---------------------------------------------------------------------------
extern "C" void kernel_launch(void* const* d_in, const int* in_sizes, int n_in,
                              void* d_out, int out_size, void* d_ws, size_t ws_size,
                              hipStream_t stream)
{
    (void)in_sizes; (void)n_in; (void)out_size; (void)ws_size;
    const float* q   = (const float*)d_in[0];
    const float* cws = (const float*)d_in[1];
    const float* KB  = (const float*)d_in[2];
    const float* c0  = (const float*)d_in[3];
    const float* m0  = (const float*)d_in[4];
    const float* Wq  = (const float*)d_in[5];
    const float* bq  = (const float*)d_in[6];
    const float* Wct = (const float*)d_in[7];
    const float* bct = (const float*)d_in[8];
    const float* wca = (const float*)d_in[9];
    const float* bca = (const float*)d_in[10];
    const float* Wm  = (const float*)d_in[11];
    const float* bm  = (const float*)d_in[12];
    const float* Wkb = (const float*)d_in[13];
    // d_in[14] = bkb : softmax-shift-invariant, dropped
    const float* Wrm = (const float*)d_in[15];
    // d_in[16] = brm, d_in[18] = bra : dropped (softmax-shift-invariant)
    const float* wra = (const float*)d_in[17];
    const float* Wwm = (const float*)d_in[19];
    const float* bwm = (const float*)d_in[20];
    const float* wwa = (const float*)d_in[21];
    const float* bwa = (const float*)d_in[22];
    const float* Wam = (const float*)d_in[23];
    const float* bam = (const float*)d_in[24];
    const float* Wg  = (const float*)d_in[25];
    const float* bg  = (const float*)d_in[26];
    // d_in[27] = steps == 12 (hardcoded TT)

    float* ws     = (float*)d_ws;
    float* q_i    = ws;
    float* c_hist = ws + 1*BD;       // 13*BD
    float* m_hist = ws + 14*BD;      // 13*BD
    float* cqb    = ws + 27*BD;
    float* mp     = ws + 28*BD;
    float* vbuf   = ws + 29*BD;
    float* w1     = ws + 30*BD;
    float* vW     = ws + 31*BD;
    float* gbuf   = ws + 32*BD;
    float* m_sa   = ws + 33*BD;
    float* m_new  = ws + 34*BD;
    float* ybuf   = ws + 35*BD;
    float* rlogp  = ws + 36*BD;      // 4*BD
    float* WrmT   = ws + 40*BD;      // 8*BD (512x1024)
    float* WkbT   = ws + 48*BD;      // 4*BD
    float* WA     = ws + 52*BD;      // 4*BD
    float* WB     = ws + 56*BD;      // 4*BD
    float* qct    = ws + 60*BD;      // 1*BD
    float* b2     = ws + 61*BD;      // 512
    float* cwsT   = ws + 62*BD;      // 30*BD (128*30*512)

    const float* Wct_bot = Wct + 262144;   // rows 512..1023
    const float* Wam_bot = Wam + 262144;
    const float* Wwm_bot = Wwm + 262144;
    dim3 blk(256);
    GDesc Z = { nullptr,nullptr,nullptr, nullptr,nullptr,nullptr,
                nullptr, nullptr, nullptr,nullptr,nullptr, 1,6,0,512 };

    // ---- setup ----
    init_hist<<<dim3(BD/256), blk, 0, stream>>>(c0, m0, c_hist, m_hist);
    transpose_k<<<dim3(16,32), blk, 0, stream>>>(Wrm, WrmT, 1024, 512);
    transpose_k<<<dim3(16,16), blk, 0, stream>>>(Wkb, WkbT, 512, 512);
    transpose_cws<<<dim3(128,16), blk, 0, stream>>>(cws, cwsT);

    {   // q_i = q@Wq + bq
        GDesc d = { q,nullptr,nullptr, Wq,nullptr,nullptr, bq, q_i,
                    nullptr,nullptr,nullptr, 1,0,8,512 };
        gemm4<<<dim3(32,8,1), blk, 0, stream>>>(d, Z);
    }
    {   // qct = q_i@Wct_top + bct
        GDesc d = { q_i,nullptr,nullptr, Wct,nullptr,nullptr, bct, qct,
                    nullptr,nullptr,nullptr, 1,0,8,512 };
        gemm4<<<dim3(32,8,1), blk, 0, stream>>>(d, Z);
    }
    {   // WA = Wwm_top@Wam_bot ; WB = Wwm_bot@Wam_bot  (M=512)
        GDesc da = { Wwm,nullptr,nullptr, Wam_bot,nullptr,nullptr, nullptr,
                     WA, nullptr,nullptr,nullptr, 1,6,8,512 };
        GDesc db = { Wwm_bot,nullptr,nullptr, Wam_bot,nullptr,nullptr, nullptr,
                     WB, nullptr,nullptr,nullptr, 1,6,8,512 };
        gemm4<<<dim3(128,8,2), blk, 0, stream>>>(da, db);
    }
    vecmat<<<dim3(8), blk, 0, stream>>>(bwm, Wam_bot, bam, b2);

    // ---- recurrence ----
    for (int t = 0; t < TT; ++t) {
        float* c_prev = c_hist + (size_t)t * BD;
        float* m_prev = m_hist + (size_t)t * BD;
        float* c_i    = c_hist + (size_t)(t+1) * BD;

        {   // cq = c_prev@Wct_bot + qct  ||  mp = m_prev@Wm + bm
            GDesc da = { c_prev,nullptr,nullptr, Wct_bot,nullptr,nullptr,
                         nullptr, cqb, qct,nullptr,nullptr, 1,4,8,512 };
            GDesc db = { m_prev,nullptr,nullptr, Wm,nullptr,nullptr,
                         bm, mp, nullptr,nullptr,nullptr, 1,0,8,512 };
            gemm4<<<dim3(32,8,2), blk, 0, stream>>>(da, db);
        }

        step_control<<<dim3(BB), dim3(512), 0, stream>>>(
            cqb, cws, cwsT, wca, bca, wra, wwa, bwa,
            c_hist, m_hist, vbuf, m_sa, t);

        {   // [w1|vW] = v@WrmT (w1 = u*mp)  ||  g = sigmoid(c_i@Wg+bg)
            GDesc da = { vbuf,nullptr,nullptr, WrmT,nullptr,nullptr,
                         nullptr, w1, mp,nullptr,vW, 1,3,16,1024 };
            GDesc db = { c_i,nullptr,nullptr, Wg,nullptr,nullptr,
                         bg, gbuf, nullptr,nullptr,nullptr, 1,1,8,512 };
            gemm4<<<dim3(32,16,2), blk, 0, stream>>>(da, db);
        }

        {   // y = w1@WkbT + vW
            GDesc d = { w1,nullptr,nullptr, WkbT,nullptr,nullptr,
                        nullptr, ybuf, vW,nullptr,nullptr, 1,4,8,512 };
            gemm4<<<dim3(32,8,1), blk, 0, stream>>>(d, Z);
        }

        read1<<<dim3(BB,8), blk, 0, stream>>>(KB, ybuf, rlogp);
        read2<<<dim3(BB,8), blk, 0, stream>>>(KB, rlogp, m_new);

        {   // m_out = gate( m_sa@Wam_top + m_new@WA + m_prev@WB + b2 )
            float* mout = (t == TT-1) ? (float*)d_out
                                      : (m_hist + (size_t)(t+1) * BD);
            GDesc d = { m_sa, m_new, m_prev, Wam, WA, WB,
                        b2, mout, gbuf, m_prev, nullptr, 3,2,8,512 };
            gemm4<<<dim3(32,8,1), blk, 0, stream>>>(d, Z);
        }
    }
}

// Round 5
// 1035.841 us; speedup vs baseline: 1.4733x; 1.2094x over previous
//
#include <hip/hip_runtime.h>
#include <cstdint>

#define BB 128
#define DD 512
#define SS 30
#define PP 196
#define TT 12
#define BD (BB*DD)

// ---------------------------------------------------------------------------
// gemm4<N>: out[m0..m0+4, nchunk] = epi( sum over nparts*512 K of A_p @ W_p ).
// N compile-time -> W-load offsets fold to immediates; wave id SGPR-ized via
// readfirstlane -> A-row reads become scalar (s_load) broadcasts.
// block = 256 (4 waves; wave w owns k in [w*128,w*128+128) of each part).
// grid (M/4, N/64, z) -- z selects descriptor.
// epi: 0 +bias | 1 sigmoid(+bias) | 2 gate(g=e1, mprev=e2, +bias)
//      3 N=1024 split: n<512 -> out=acc*e1 ; n>=512 -> o2=acc  (no bias)
//      4 out = acc + e1[m,n] (row addend) | 6 raw
// ---------------------------------------------------------------------------
struct GDesc {
    const float* A0; const float* A1; const float* A2;
    const float* W0; const float* W1; const float* W2;
    const float* bias;
    float* out;
    const float* e1; const float* e2; float* o2;
    int nparts, epi, nblk;
};

template<int N>
__global__ __launch_bounds__(256)
void gemm4(GDesc da, GDesc db)
{
    GDesc d = (blockIdx.z == 0) ? da : db;
    if ((int)blockIdx.y >= d.nblk) return;
    const int lane = threadIdx.x & 63;
    const int w    = __builtin_amdgcn_readfirstlane((int)threadIdx.x >> 6);
    const int m0   = blockIdx.x * 4;
    const int n    = blockIdx.y * 64 + lane;

    float acc[4][2];
    #pragma unroll
    for (int m = 0; m < 4; ++m) { acc[m][0] = 0.f; acc[m][1] = 0.f; }

    for (int p = 0; p < d.nparts; ++p) {
        const float* __restrict__ A  = (p == 0) ? d.A0 : (p == 1 ? d.A1 : d.A2);
        const float* __restrict__ Wp = (p == 0) ? d.W0 : (p == 1 ? d.W1 : d.W2);
        const float* __restrict__ Wb = Wp + (size_t)(w * 128) * N;  // uniform base
        const float* __restrict__ a  = A + m0 * 512 + w * 128;     // uniform (SGPR)
        #pragma unroll 2
        for (int k = 0; k < 128; k += 8) {
            float w0 = Wb[n + 0*N];
            float w1 = Wb[n + 1*N];
            float w2 = Wb[n + 2*N];
            float w3 = Wb[n + 3*N];
            float w4 = Wb[n + 4*N];
            float w5 = Wb[n + 5*N];
            float w6 = Wb[n + 6*N];
            float w7 = Wb[n + 7*N];
            Wb += 8 * N;
            #pragma unroll
            for (int m = 0; m < 4; ++m) {
                const float* __restrict__ am = a + m * 512 + k;    // uniform
                float a0 = am[0], a1 = am[1], a2 = am[2], a3 = am[3];
                float a4 = am[4], a5 = am[5], a6 = am[6], a7 = am[7];
                float s0 = acc[m][0], s1 = acc[m][1];
                s0 = fmaf(a0, w0, s0);  s1 = fmaf(a4, w4, s1);
                s0 = fmaf(a1, w1, s0);  s1 = fmaf(a5, w5, s1);
                s0 = fmaf(a2, w2, s0);  s1 = fmaf(a6, w6, s1);
                s0 = fmaf(a3, w3, s0);  s1 = fmaf(a7, w7, s1);
                acc[m][0] = s0; acc[m][1] = s1;
            }
        }
    }

    __shared__ float red[4][4][64];
    #pragma unroll
    for (int m = 0; m < 4; ++m) red[w][m][lane] = acc[m][0] + acc[m][1];
    __syncthreads();

    {
        int mm = threadIdx.x >> 6, nl = threadIdx.x & 63;
        int nn = blockIdx.y * 64 + nl;
        float s = ((red[0][mm][nl] + red[1][mm][nl]) +
                   (red[2][mm][nl] + red[3][mm][nl]));
        size_t row = (size_t)(m0 + mm);
        if (d.epi == 0) {
            d.out[row*512 + nn] = s + d.bias[nn];
        } else if (d.epi == 1) {
            float v = s + d.bias[nn];
            d.out[row*512 + nn] = 1.f / (1.f + __expf(-v));
        } else if (d.epi == 2) {
            float v = s + d.bias[nn];
            float g = d.e1[row*512 + nn];
            d.out[row*512 + nn] = g * d.e2[row*512 + nn] + (1.f - g) * v;
        } else if (d.epi == 3) {
            if (nn < 512) d.out[row*512 + nn] = s * d.e1[row*512 + nn];
            else          d.o2[row*512 + (nn - 512)] = s;
        } else if (d.epi == 4) {
            d.out[row*512 + nn] = s + d.e1[row*512 + nn];
        } else {
            d.out[row*512 + nn] = s;
        }
    }
}

// ---------------------------------------------------------------------------
// vecmat: out[n] = sum_k v[k]*W[k*512+n] + bias[n].  grid 8, block 256.
// ---------------------------------------------------------------------------
__global__ __launch_bounds__(256)
void vecmat(const float* __restrict__ v, const float* __restrict__ W,
            const float* __restrict__ bias, float* __restrict__ out)
{
    int lane = threadIdx.x & 63, w = threadIdx.x >> 6;
    int n = blockIdx.x * 64 + lane;
    float s = 0.f;
    for (int k = w*128; k < w*128 + 128; ++k)
        s = fmaf(v[k], W[(size_t)k*512 + n], s);
    __shared__ float red[4][64];
    red[w][lane] = s;
    __syncthreads();
    if (threadIdx.x < 64) {
        int nn = blockIdx.x * 64 + threadIdx.x;
        out[nn] = red[0][threadIdx.x] + red[1][threadIdx.x]
                + red[2][threadIdx.x] + red[3][threadIdx.x] + bias[nn];
    }
}

// ---------------------------------------------------------------------------
// Tiled transpose: dst[c*R + r] = src[r*C + c].  grid (C/32, R/32), block 256.
// ---------------------------------------------------------------------------
__global__ __launch_bounds__(256)
void transpose_k(const float* __restrict__ src, float* __restrict__ dst,
                 int R, int C)
{
    __shared__ float tile[32][33];
    int bx = blockIdx.x * 32, by = blockIdx.y * 32;
    int tx = threadIdx.x & 31, ty = threadIdx.x >> 5;
    #pragma unroll
    for (int i = 0; i < 32; i += 8)
        tile[ty + i][tx] = src[(size_t)(by + ty + i) * C + bx + tx];
    __syncthreads();
    #pragma unroll
    for (int i = 0; i < 32; i += 8)
        dst[(size_t)(bx + ty + i) * R + by + tx] = tile[tx][ty + i];
}

// cwsT[b][s][d] = cws[b][d][s].  grid (128, 16), block 256.
__global__ __launch_bounds__(256)
void transpose_cws(const float* __restrict__ cws, float* __restrict__ cwsT)
{
    int b = blockIdx.x, dc = blockIdx.y;
    __shared__ float tile[32][33];
    int tid = threadIdx.x;
    const float* src = cws + ((size_t)b*DD + dc*32) * SS;
    for (int i = tid; i < 1024; i += 256) {
        int r = i >> 5, s = i & 31;
        if (s < SS) tile[r][s] = src[(size_t)r*SS + s];
    }
    __syncthreads();
    for (int i = tid; i < 1024; i += 256) {
        int s = i >> 5, r = i & 31;
        if (s < SS)
            cwsT[((size_t)b*SS + s)*DD + dc*32 + r] = tile[r][s];
    }
}

// ---------------------------------------------------------------------------
// step_control: per-b block (512 thr). clog (coalesced via cwsT) -> softmax ->
// c_i; writes c_hist[t+1], v=c_i*wra, self-attn m_sa.
// ---------------------------------------------------------------------------
__global__ __launch_bounds__(512)
void step_control(const float* __restrict__ cq, const float* __restrict__ cws,
                  const float* __restrict__ cwsT,
                  const float* __restrict__ wca, const float* __restrict__ bca,
                  const float* __restrict__ wra, const float* __restrict__ wwa,
                  const float* __restrict__ bwa,
                  float* __restrict__ c_hist, const float* __restrict__ m_hist,
                  float* __restrict__ vbuf, float* __restrict__ m_sa, int t)
{
    int b = blockIdx.x;
    int tid = threadIdx.x;
    int lane = tid & 63, w = tid >> 6;
    __shared__ float cqw[DD];
    __shared__ float ciw[DD];
    __shared__ float clog[32];
    __shared__ float cattn[32];
    __shared__ float slog[16];
    __shared__ float sattn[16];

    cqw[tid] = cq[(size_t)b*DD + tid] * wca[tid];
    __syncthreads();

    for (int s = w; s < SS; s += 8) {
        const float* row = cwsT + ((size_t)b*SS + s)*DD;
        float a = 0.f;
        #pragma unroll
        for (int j = 0; j < 8; ++j)
            a = fmaf(cqw[lane + 64*j], row[lane + 64*j], a);
        for (int off = 32; off; off >>= 1) a += __shfl_xor(a, off, 64);
        if (lane == 0) clog[s] = a;
    }
    __syncthreads();

    if (tid < 32) {
        float v = (tid < SS) ? clog[tid] + bca[0] : -1e30f;
        float mx = v;
        for (int off = 16; off; off >>= 1) mx = fmaxf(mx, __shfl_xor(mx, off, 32));
        float e = (tid < SS) ? __expf(v - mx) : 0.f;
        float sm = e;
        for (int off = 16; off; off >>= 1) sm += __shfl_xor(sm, off, 32);
        cattn[tid] = e / sm;
    }
    __syncthreads();

    {   // c_i: thread-per-d, contiguous 30-float read
        int d = tid;
        const float* base = cws + (size_t)b*DD*SS + (size_t)d*SS;
        float acc = 0.f;
        #pragma unroll
        for (int j = 0; j < SS; ++j) acc = fmaf(cattn[j], base[j], acc);
        c_hist[(size_t)(t+1)*BD + (size_t)b*DD + d] = acc;
        vbuf[(size_t)b*DD + d] = acc * wra[d];
        ciw[d] = acc * wwa[d];
    }
    __syncthreads();

    for (int tp = w; tp <= t; tp += 8) {
        const float* ch = c_hist + (size_t)tp*BD + (size_t)b*DD;
        float a = 0.f;
        #pragma unroll
        for (int j = 0; j < 8; ++j)
            a = fmaf(ciw[lane + 64*j], ch[lane + 64*j], a);
        for (int off = 32; off; off >>= 1) a += __shfl_xor(a, off, 64);
        if (lane == 0) slog[tp] = a;
    }
    __syncthreads();

    if (tid < 16) {
        float v = (tid <= t) ? (slog[tid] + bwa[0]) : -1e30f;
        float mx = v;
        for (int off = 8; off; off >>= 1) mx = fmaxf(mx, __shfl_xor(mx, off, 16));
        float e = (tid <= t) ? __expf(v - mx) : 0.f;
        float sm = e;
        for (int off = 8; off; off >>= 1) sm += __shfl_xor(sm, off, 16);
        sattn[tid] = e / sm;
    }
    __syncthreads();

    {   // m_sa: thread-per-d
        int d = tid;
        float acc = 0.f;
        for (int tp = 0; tp <= t; ++tp)
            acc = fmaf(sattn[tp], m_hist[(size_t)tp*BD + (size_t)b*DD + d], acc);
        m_sa[(size_t)b*DD + d] = acc;
    }
}

// ---------------------------------------------------------------------------
// read1: block (b, dg). Partial rlog over 64-d slice: rlog_p = KB.y
// ---------------------------------------------------------------------------
__global__ __launch_bounds__(256)
void read1(const float* __restrict__ KB, const float* __restrict__ y,
           float* __restrict__ rlogp)
{
    int b = blockIdx.x, dg = blockIdx.y, tid = threadIdx.x;
    __shared__ float yb[64];
    if (tid < 64) yb[tid] = y[(size_t)b*DD + dg*64 + tid];
    __syncthreads();
    float a0=0.f, a1=0.f, a2=0.f, a3=0.f;
    if (tid < PP) {
        const float* kb = KB + ((size_t)b*DD + dg*64)*PP + tid;
        #pragma unroll 4
        for (int dd = 0; dd < 64; dd += 4) {
            a0 = fmaf(kb[(size_t)(dd+0)*PP], yb[dd+0], a0);
            a1 = fmaf(kb[(size_t)(dd+1)*PP], yb[dd+1], a1);
            a2 = fmaf(kb[(size_t)(dd+2)*PP], yb[dd+2], a2);
            a3 = fmaf(kb[(size_t)(dd+3)*PP], yb[dd+3], a3);
        }
    }
    rlogp[((size_t)b*8 + dg)*256 + tid] = (a0+a1)+(a2+a3);
}

// ---------------------------------------------------------------------------
// read2: reduce partials -> softmax(196) -> m_new 64-d slice.
// ---------------------------------------------------------------------------
__global__ __launch_bounds__(256)
void read2(const float* __restrict__ KB, const float* __restrict__ rlogp,
           float* __restrict__ m_new)
{
    int b = blockIdx.x, dg = blockIdx.y;
    int tid = threadIdx.x, lane = tid & 63, w = tid >> 6;
    __shared__ float ex[256];
    __shared__ float wred[4];

    float v = -1e30f;
    if (tid < PP) {
        const float* rp = rlogp + (size_t)b*2048 + tid;
        float t0 = rp[0]    + rp[256];
        float t1 = rp[512]  + rp[768];
        float t2 = rp[1024] + rp[1280];
        float t3 = rp[1536] + rp[1792];
        v = (t0+t1)+(t2+t3);
    }
    float mx = v;
    for (int off = 32; off; off >>= 1) mx = fmaxf(mx, __shfl_xor(mx, off, 64));
    if (lane == 0) wred[w] = mx;
    __syncthreads();
    float gmax = fmaxf(fmaxf(wred[0], wred[1]), fmaxf(wred[2], wred[3]));
    float e = (tid < PP) ? __expf(v - gmax) : 0.f;
    float sm = e;
    for (int off = 32; off; off >>= 1) sm += __shfl_xor(sm, off, 64);
    __syncthreads();
    if (lane == 0) wred[w] = sm;
    __syncthreads();
    float inv = 1.f / ((wred[0]+wred[1]) + (wred[2]+wred[3]));
    ex[tid] = e * inv;
    __syncthreads();

    #pragma unroll 4
    for (int i = 0; i < 16; ++i) {
        int d = dg*64 + w*16 + i;
        const float* row = KB + ((size_t)b*DD + d)*PP;
        float a = ex[lane]       * row[lane]
                + ex[lane + 64]  * row[lane + 64]
                + ex[lane + 128] * row[lane + 128];
        if (lane < PP - 192) a = fmaf(ex[lane + 192], row[lane + 192], a);
        for (int off = 32; off; off >>= 1) a += __shfl_xor(a, off, 64);
        if (lane == 0) m_new[(size_t)b*DD + d] = a;
    }
}

__global__ __launch_bounds__(256)
void init_hist(const float* __restrict__ c0, const float* __restrict__ m0,
               float* __restrict__ c_hist, float* __restrict__ m_hist)
{
    int i = blockIdx.x * 256 + threadIdx.x;
    if (i < BD) { c_hist[i] = c0[i]; m_hist[i] = m0[i]; }
}

// ---------------------------------------------------------------------------
extern "C" void kernel_launch(void* const* d_in, const int* in_sizes, int n_in,
                              void* d_out, int out_size, void* d_ws, size_t ws_size,
                              hipStream_t stream)
{
    (void)in_sizes; (void)n_in; (void)out_size; (void)ws_size;
    const float* q   = (const float*)d_in[0];
    const float* cws = (const float*)d_in[1];
    const float* KB  = (const float*)d_in[2];
    const float* c0  = (const float*)d_in[3];
    const float* m0  = (const float*)d_in[4];
    const float* Wq  = (const float*)d_in[5];
    const float* bq  = (const float*)d_in[6];
    const float* Wct = (const float*)d_in[7];
    const float* bct = (const float*)d_in[8];
    const float* wca = (const float*)d_in[9];
    const float* bca = (const float*)d_in[10];
    const float* Wm  = (const float*)d_in[11];
    const float* bm  = (const float*)d_in[12];
    const float* Wkb = (const float*)d_in[13];
    // d_in[14] = bkb : softmax-shift-invariant, dropped
    const float* Wrm = (const float*)d_in[15];
    // d_in[16] = brm, d_in[18] = bra : dropped (softmax-shift-invariant)
    const float* wra = (const float*)d_in[17];
    const float* Wwm = (const float*)d_in[19];
    const float* bwm = (const float*)d_in[20];
    const float* wwa = (const float*)d_in[21];
    const float* bwa = (const float*)d_in[22];
    const float* Wam = (const float*)d_in[23];
    const float* bam = (const float*)d_in[24];
    const float* Wg  = (const float*)d_in[25];
    const float* bg  = (const float*)d_in[26];
    // d_in[27] = steps == 12 (hardcoded TT)

    float* ws     = (float*)d_ws;
    float* q_i    = ws;
    float* c_hist = ws + 1*BD;       // 13*BD
    float* m_hist = ws + 14*BD;      // 13*BD
    float* cqb    = ws + 27*BD;
    float* mp     = ws + 28*BD;
    float* vbuf   = ws + 29*BD;
    float* w1     = ws + 30*BD;
    float* vW     = ws + 31*BD;
    float* gbuf   = ws + 32*BD;
    float* m_sa   = ws + 33*BD;
    float* m_new  = ws + 34*BD;
    float* ybuf   = ws + 35*BD;
    float* rlogp  = ws + 36*BD;      // 4*BD
    float* WrmT   = ws + 40*BD;      // 8*BD (512x1024)
    float* WkbT   = ws + 48*BD;      // 4*BD
    float* WA     = ws + 52*BD;      // 4*BD
    float* WB     = ws + 56*BD;      // 4*BD
    float* qct    = ws + 60*BD;      // 1*BD
    float* b2     = ws + 61*BD;      // 512
    float* cwsT   = ws + 62*BD;      // 30*BD (128*30*512)

    const float* Wct_bot = Wct + 262144;   // rows 512..1023
    const float* Wam_bot = Wam + 262144;
    const float* Wwm_bot = Wwm + 262144;
    dim3 blk(256);
    GDesc Z = { nullptr,nullptr,nullptr, nullptr,nullptr,nullptr,
                nullptr, nullptr, nullptr,nullptr,nullptr, 1,6,0 };

    // ---- setup ----
    init_hist<<<dim3(BD/256), blk, 0, stream>>>(c0, m0, c_hist, m_hist);
    transpose_k<<<dim3(16,32), blk, 0, stream>>>(Wrm, WrmT, 1024, 512);
    transpose_k<<<dim3(16,16), blk, 0, stream>>>(Wkb, WkbT, 512, 512);
    transpose_cws<<<dim3(128,16), blk, 0, stream>>>(cws, cwsT);

    {   // q_i = q@Wq + bq
        GDesc d = { q,nullptr,nullptr, Wq,nullptr,nullptr, bq, q_i,
                    nullptr,nullptr,nullptr, 1,0,8 };
        gemm4<512><<<dim3(32,8,1), blk, 0, stream>>>(d, Z);
    }
    {   // qct = q_i@Wct_top + bct
        GDesc d = { q_i,nullptr,nullptr, Wct,nullptr,nullptr, bct, qct,
                    nullptr,nullptr,nullptr, 1,0,8 };
        gemm4<512><<<dim3(32,8,1), blk, 0, stream>>>(d, Z);
    }
    {   // WA = Wwm_top@Wam_bot ; WB = Wwm_bot@Wam_bot  (M=512)
        GDesc da = { Wwm,nullptr,nullptr, Wam_bot,nullptr,nullptr, nullptr,
                     WA, nullptr,nullptr,nullptr, 1,6,8 };
        GDesc db = { Wwm_bot,nullptr,nullptr, Wam_bot,nullptr,nullptr, nullptr,
                     WB, nullptr,nullptr,nullptr, 1,6,8 };
        gemm4<512><<<dim3(128,8,2), blk, 0, stream>>>(da, db);
    }
    vecmat<<<dim3(8), blk, 0, stream>>>(bwm, Wam_bot, bam, b2);

    // ---- recurrence ----
    for (int t = 0; t < TT; ++t) {
        float* c_prev = c_hist + (size_t)t * BD;
        float* m_prev = m_hist + (size_t)t * BD;
        float* c_i    = c_hist + (size_t)(t+1) * BD;

        {   // cq = c_prev@Wct_bot + qct  ||  mp = m_prev@Wm + bm
            GDesc da = { c_prev,nullptr,nullptr, Wct_bot,nullptr,nullptr,
                         nullptr, cqb, qct,nullptr,nullptr, 1,4,8 };
            GDesc db = { m_prev,nullptr,nullptr, Wm,nullptr,nullptr,
                         bm, mp, nullptr,nullptr,nullptr, 1,0,8 };
            gemm4<512><<<dim3(32,8,2), blk, 0, stream>>>(da, db);
        }

        step_control<<<dim3(BB), dim3(512), 0, stream>>>(
            cqb, cws, cwsT, wca, bca, wra, wwa, bwa,
            c_hist, m_hist, vbuf, m_sa, t);

        {   // [w1|vW] = v@WrmT (w1 = u*mp)
            GDesc d = { vbuf,nullptr,nullptr, WrmT,nullptr,nullptr,
                        nullptr, w1, mp,nullptr,vW, 1,3,16 };
            gemm4<1024><<<dim3(32,16,1), blk, 0, stream>>>(d, d);
        }

        {   // y = w1@WkbT + vW  ||  g = sigmoid(c_i@Wg+bg)
            GDesc da = { w1,nullptr,nullptr, WkbT,nullptr,nullptr,
                         nullptr, ybuf, vW,nullptr,nullptr, 1,4,8 };
            GDesc db = { c_i,nullptr,nullptr, Wg,nullptr,nullptr,
                         bg, gbuf, nullptr,nullptr,nullptr, 1,1,8 };
            gemm4<512><<<dim3(32,8,2), blk, 0, stream>>>(da, db);
        }

        read1<<<dim3(BB,8), blk, 0, stream>>>(KB, ybuf, rlogp);
        read2<<<dim3(BB,8), blk, 0, stream>>>(KB, rlogp, m_new);

        {   // m_out = gate( m_sa@Wam_top + m_new@WA + m_prev@WB + b2 )
            float* mout = (t == TT-1) ? (float*)d_out
                                      : (m_hist + (size_t)(t+1) * BD);
            GDesc d = { m_sa, m_new, m_prev, Wam, WA, WB,
                        b2, mout, gbuf, m_prev, nullptr, 3,2,8 };
            gemm4<512><<<dim3(32,8,1), blk, 0, stream>>>(d, Z);
        }
    }
}